// Round 3
// baseline (532.879 us; speedup 1.0000x reference)
//
#include <hip/hip_runtime.h>

// EdgeFormerINT4Linear via INT8 dynamic quantization.
// Round 3: restructured K-loop — single barrier/iter, A double-buffered in LDS
// (global_load_lds width-16), B fragments loaded global->VGPR directly
// (L2-resident, bypasses LDS + barrier dependency). Pre-passes fused.

#define M_ROWS 8192
#define N_COLS 4096
#define K_DIM  4096

typedef int int32x4 __attribute__((ext_vector_type(4)));

__device__ __forceinline__ void async16(const void* g, void* l) {
  __builtin_amdgcn_global_load_lds(
      (const __attribute__((address_space(1))) void*)g,
      (__attribute__((address_space(3))) void*)l,
      16 /*bytes*/, 0 /*offset*/, 0 /*aux*/);
}

// ---- fused pre-pass ----
// blocks [0, 8192): per-row symmetric int8 quant of x (256 thr x 16 elems)
// blocks [8192, 8192+16384): q int32 -> int8 pack (4 elems/thread)
__global__ __launch_bounds__(256) void prep_kernel(const float4* __restrict__ x,
                                                   int* __restrict__ xq,
                                                   float* __restrict__ srow,
                                                   const int4* __restrict__ q,
                                                   int* __restrict__ q8) {
  const int t = threadIdx.x;
  if (blockIdx.x < M_ROWS) {
    const int row = blockIdx.x;
    const float4* xr = x + (size_t)row * (K_DIM / 4);
    float4 v[4];
    float am = 0.f;
#pragma unroll
    for (int j = 0; j < 4; ++j) {
      v[j] = xr[t + 256 * j];
      am = fmaxf(am, fmaxf(fmaxf(fabsf(v[j].x), fabsf(v[j].y)),
                           fmaxf(fabsf(v[j].z), fabsf(v[j].w))));
    }
#pragma unroll
    for (int off = 32; off > 0; off >>= 1)
      am = fmaxf(am, __shfl_down(am, off, 64));
    __shared__ float wmax[4];
    if ((t & 63) == 0) wmax[t >> 6] = am;
    __syncthreads();
    am = fmaxf(fmaxf(wmax[0], wmax[1]), fmaxf(wmax[2], wmax[3]));
    const float inv = (am > 0.f) ? 127.f / am : 0.f;
    if (t == 0) srow[row] = am * (1.f / 127.f);
    int* o = xq + (size_t)row * (K_DIM / 4);
#pragma unroll
    for (int j = 0; j < 4; ++j) {
      int a = __float2int_rn(v[j].x * inv);
      int b = __float2int_rn(v[j].y * inv);
      int c = __float2int_rn(v[j].z * inv);
      int d = __float2int_rn(v[j].w * inv);
      o[t + 256 * j] = (a & 0xff) | ((b & 0xff) << 8) | ((c & 0xff) << 16) | (d << 24);
    }
  } else {
    const int i = (blockIdx.x - M_ROWS) * 256 + t;
    int4 v = q[i];
    q8[i] = (v.x & 0xff) | ((v.y & 0xff) << 8) | ((v.z & 0xff) << 16) | (v.w << 24);
  }
}

// ---- GEMM: A[M,K] int8, B[N,K] int8 (B^T form) ----
// Block 256 thr (4 waves), tile 128x128, BK=128. One __syncthreads per iter:
//   sync -> stage A(it+1) into buf^1 + load B(it) frags to VGPR -> 32 MFMAs.
// sA chunk layout XOR-swizzled (verified 0 bank conflicts).
__global__ __launch_bounds__(256, 3) void gemm_i8_kernel(
    const char* __restrict__ A, const char* __restrict__ B,
    const float* __restrict__ scale, const float* __restrict__ srow,
    const float* __restrict__ bias, float* __restrict__ out) {
  __shared__ __attribute__((aligned(16))) char sA[2][128 * 128];

  const int tid  = threadIdx.x;
  const int lane = tid & 63;
  const int w    = tid >> 6;
  const int wr   = w >> 1;
  const int wc   = w & 1;
  const int lm   = lane & 15;
  const int lk   = lane >> 4;

  const int m0 = blockIdx.y * 128;
  const int n0 = blockIdx.x * 128;

  int32x4 acc[4][4];
#pragma unroll
  for (int i = 0; i < 4; ++i)
#pragma unroll
    for (int j = 0; j < 4; ++j)
      acc[i][j] = (int32x4){0, 0, 0, 0};

  // invariant per-thread A-staging coords: 4 chunks of 16B
  int st_r[4], st_sc[4], st_ch[4];
#pragma unroll
  for (int i = 0; i < 4; ++i) {
    const int ch = i * 256 + tid;
    st_ch[i] = ch;
    st_r[i]  = ch >> 3;
    st_sc[i] = (ch & 7) ^ (st_r[i] & 7);
  }
  // invariant B row bases for this wave's 4 n-tiles
  const char* Brow[4];
#pragma unroll
  for (int j = 0; j < 4; ++j)
    Brow[j] = B + (size_t)(n0 + wc * 64 + j * 16 + lm) * K_DIM;

  constexpr int NIT = K_DIM / 128;

  // prologue: stage A(0) into buf 0
#pragma unroll
  for (int i = 0; i < 4; ++i)
    async16(A + (size_t)(m0 + st_r[i]) * K_DIM + st_sc[i] * 16,
            sA[0] + st_ch[i] * 16);

  for (int it = 0; it < NIT; ++it) {
    __syncthreads();                       // drains A(it) staging
    const int cb = it & 1;
    if (it < NIT - 1) {                    // stage A(it+1) into other buffer
      const int k1 = (it + 1) * 128;
#pragma unroll
      for (int i = 0; i < 4; ++i)
        async16(A + (size_t)(m0 + st_r[i]) * K_DIM + k1 + st_sc[i] * 16,
                sA[cb ^ 1] + st_ch[i] * 16);
    }
    // B fragments for this iter: global->VGPR, L2-resident
    int32x4 bfr[2][4];
    const size_t kb = (size_t)it * 128;
#pragma unroll
    for (int ks = 0; ks < 2; ++ks)
#pragma unroll
      for (int j = 0; j < 4; ++j)
        bfr[ks][j] = *(const int32x4*)(Brow[j] + kb + (ks * 4 + lk) * 16);

#pragma unroll
    for (int ks = 0; ks < 2; ++ks) {
      const int kc = ks * 4 + lk;
      int32x4 af[4];
#pragma unroll
      for (int i = 0; i < 4; ++i) {
        const int row = wr * 64 + i * 16 + lm;
        af[i] = *(const int32x4*)(sA[cb] + ((row * 8) + (kc ^ (row & 7))) * 16);
      }
#pragma unroll
      for (int i = 0; i < 4; ++i)
#pragma unroll
        for (int j = 0; j < 4; ++j)
          acc[i][j] = __builtin_amdgcn_mfma_i32_16x16x64_i8(af[i], bfr[ks][j],
                                                            acc[i][j], 0, 0, 0);
    }
  }

  // epilogue: C/D layout col=lane&15 (n), row=(lane>>4)*4+reg (m)
#pragma unroll
  for (int j = 0; j < 4; ++j) {
    const int o    = n0 + wc * 64 + j * 16 + lm;
    const float so = scale[o];
    const float bz = bias[o];
#pragma unroll
    for (int i = 0; i < 4; ++i) {
      const int mbase = m0 + wr * 64 + i * 16 + lk * 4;
#pragma unroll
      for (int r = 0; r < 4; ++r) {
        const int m = mbase + r;
        out[(size_t)m * N_COLS + o] = (float)acc[i][j][r] * (so * srow[m]) + bz;
      }
    }
  }
}

extern "C" void kernel_launch(void* const* d_in, const int* in_sizes, int n_in,
                              void* d_out, int out_size, void* d_ws, size_t ws_size,
                              hipStream_t stream) {
  const float* x     = (const float*)d_in[0];   // [4,2048,4096] fp32
  const int*   q     = (const int*)d_in[1];     // [4096,4096] int32 in [-8,7]
  const float* scale = (const float*)d_in[2];   // [4096]
  const float* bias  = (const float*)d_in[3];   // [4096]
  float* out = (float*)d_out;                   // [8192,4096] fp32

  // workspace: A8 (32 MiB) | B8 (16 MiB) | srow (32 KiB)
  char*  A8   = (char*)d_ws;
  char*  B8   = (char*)d_ws + (size_t)M_ROWS * K_DIM;
  float* srow = (float*)((char*)B8 + (size_t)N_COLS * K_DIM);

  // 8192 quant blocks + 16384 pack blocks
  prep_kernel<<<M_ROWS + (N_COLS * K_DIM / 4) / 256, 256, 0, stream>>>(
      (const float4*)x, (int*)A8, srow, (const int4*)q, (int*)B8);

  dim3 grid(N_COLS / 128, M_ROWS / 128);  // 32 x 64 = 2048 blocks
  gemm_i8_kernel<<<grid, 256, 0, stream>>>(A8, B8, scale, srow, bias, out);
}

// Round 4
// 417.993 us; speedup vs baseline: 1.2749x; 1.2749x over previous
//
#include <hip/hip_runtime.h>

// EdgeFormerINT4Linear via INT8 dynamic quantization.
// Round 4: revert B to LDS staging (round-3 global-gather was 16 txn/instr —
// uncoalesced, 2.2x regression). New: BK=64 with BOTH tiles double-buffered
// (2 x 16 KB = 32 KB LDS, occupancy preserved), ONE barrier per K-iter with
// prefetch issued right after it (drain waits on a transfer issued a full
// compute phase earlier), 8x8 supertile grid swizzle for L2 locality.

#define M_ROWS 8192
#define N_COLS 4096
#define K_DIM  4096

typedef int int32x4 __attribute__((ext_vector_type(4)));

__device__ __forceinline__ void async16(const void* g, void* l) {
  __builtin_amdgcn_global_load_lds(
      (const __attribute__((address_space(1))) void*)g,
      (__attribute__((address_space(3))) void*)l,
      16 /*bytes*/, 0 /*offset*/, 0 /*aux*/);
}

// ---- fused pre-pass ----
// blocks [0, 8192): per-row symmetric int8 quant of x (256 thr x 16 elems)
// blocks [8192, 8192+16384): q int32 -> int8 pack (4 elems/thread)
__global__ __launch_bounds__(256) void prep_kernel(const float4* __restrict__ x,
                                                   int* __restrict__ xq,
                                                   float* __restrict__ srow,
                                                   const int4* __restrict__ q,
                                                   int* __restrict__ q8) {
  const int t = threadIdx.x;
  if (blockIdx.x < M_ROWS) {
    const int row = blockIdx.x;
    const float4* xr = x + (size_t)row * (K_DIM / 4);
    float4 v[4];
    float am = 0.f;
#pragma unroll
    for (int j = 0; j < 4; ++j) {
      v[j] = xr[t + 256 * j];
      am = fmaxf(am, fmaxf(fmaxf(fabsf(v[j].x), fabsf(v[j].y)),
                           fmaxf(fabsf(v[j].z), fabsf(v[j].w))));
    }
#pragma unroll
    for (int off = 32; off > 0; off >>= 1)
      am = fmaxf(am, __shfl_down(am, off, 64));
    __shared__ float wmax[4];
    if ((t & 63) == 0) wmax[t >> 6] = am;
    __syncthreads();
    am = fmaxf(fmaxf(wmax[0], wmax[1]), fmaxf(wmax[2], wmax[3]));
    const float inv = (am > 0.f) ? 127.f / am : 0.f;
    if (t == 0) srow[row] = am * (1.f / 127.f);
    int* o = xq + (size_t)row * (K_DIM / 4);
#pragma unroll
    for (int j = 0; j < 4; ++j) {
      int a = __float2int_rn(v[j].x * inv);
      int b = __float2int_rn(v[j].y * inv);
      int c = __float2int_rn(v[j].z * inv);
      int d = __float2int_rn(v[j].w * inv);
      o[t + 256 * j] = (a & 0xff) | ((b & 0xff) << 8) | ((c & 0xff) << 16) | (d << 24);
    }
  } else {
    const int i = (blockIdx.x - M_ROWS) * 256 + t;
    int4 v = q[i];
    q8[i] = (v.x & 0xff) | ((v.y & 0xff) << 8) | ((v.z & 0xff) << 16) | (v.w << 24);
  }
}

// ---- GEMM: A[M,K] int8, B[N,K] int8 (B^T form) ----
// Block 256 thr (4 waves), tile 128x128, BK=64, double-buffered A+B in LDS.
// Per iter: one __syncthreads (drains prefetch issued last iter), issue
// prefetch(it+1) into other buffer, 8 ds_read_b128 + 16 MFMAs from current.
// LDS chunk swizzle: tile row r (64 B = 4 chunks), global chunk c stored at
// slot c ^ ((r>>1)&3) -> fragment read is 32 banks x 2-way (free).
__global__ __launch_bounds__(256, 4) void gemm_i8_kernel(
    const char* __restrict__ A, const char* __restrict__ B,
    const float* __restrict__ scale, const float* __restrict__ srow,
    const float* __restrict__ bias, float* __restrict__ out) {
  __shared__ __attribute__((aligned(16))) char sA[2][128 * 64];
  __shared__ __attribute__((aligned(16))) char sB[2][128 * 64];

  const int tid  = threadIdx.x;
  const int lane = tid & 63;
  const int w    = tid >> 6;
  const int wr   = w >> 1;
  const int wc   = w & 1;
  const int lm   = lane & 15;
  const int lk   = lane >> 4;   // k-chunk 0..3 (16 B each)

  // 8x8 supertile swizzle: 64 consecutive block IDs cover 1024x1024 output
  const int bid    = blockIdx.x;        // 0..2047
  const int super  = bid >> 6;          // 0..31  (8 m-super x 4 n-super)
  const int within = bid & 63;
  const int m0 = ((super >> 2) * 8 + (within >> 3)) * 128;
  const int n0 = ((super & 3) * 8 + (within & 7)) * 128;

  int32x4 acc[4][4];
#pragma unroll
  for (int i = 0; i < 4; ++i)
#pragma unroll
    for (int j = 0; j < 4; ++j)
      acc[i][j] = (int32x4){0, 0, 0, 0};

  // staging coords: 512 chunks/tile, 2 per thread per tile
  int st_r[2], st_sc[2], st_ch[2];
#pragma unroll
  for (int i = 0; i < 2; ++i) {
    const int ch = i * 256 + tid;
    st_ch[i] = ch;
    st_r[i]  = ch >> 2;
    st_sc[i] = (ch & 3) ^ ((st_r[i] >> 1) & 3);
  }

  constexpr int NIT = K_DIM / 64;

  // prologue: stage tiles(0) into buffer 0
#pragma unroll
  for (int i = 0; i < 2; ++i) {
    async16(A + (size_t)(m0 + st_r[i]) * K_DIM + st_sc[i] * 16,
            sA[0] + st_ch[i] * 16);
    async16(B + (size_t)(n0 + st_r[i]) * K_DIM + st_sc[i] * 16,
            sB[0] + st_ch[i] * 16);
  }

  for (int it = 0; it < NIT; ++it) {
    const int cb = it & 1;
    __syncthreads();                     // drains stage(it), issued 1 iter ago
    if (it < NIT - 1) {
      const int k1 = (it + 1) * 64;
#pragma unroll
      for (int i = 0; i < 2; ++i) {
        async16(A + (size_t)(m0 + st_r[i]) * K_DIM + k1 + st_sc[i] * 16,
                sA[cb ^ 1] + st_ch[i] * 16);
        async16(B + (size_t)(n0 + st_r[i]) * K_DIM + k1 + st_sc[i] * 16,
                sB[cb ^ 1] + st_ch[i] * 16);
      }
    }
    int32x4 af[4], bfr[4];
#pragma unroll
    for (int i = 0; i < 4; ++i) {
      const int row = wr * 64 + i * 16 + lm;
      af[i] = *(const int32x4*)(sA[cb] + (row * 4 + (lk ^ ((row >> 1) & 3))) * 16);
    }
#pragma unroll
    for (int j = 0; j < 4; ++j) {
      const int row = wc * 64 + j * 16 + lm;
      bfr[j] = *(const int32x4*)(sB[cb] + (row * 4 + (lk ^ ((row >> 1) & 3))) * 16);
    }
#pragma unroll
    for (int i = 0; i < 4; ++i)
#pragma unroll
      for (int j = 0; j < 4; ++j)
        acc[i][j] = __builtin_amdgcn_mfma_i32_16x16x64_i8(af[i], bfr[j],
                                                          acc[i][j], 0, 0, 0);
  }

  // epilogue: C/D layout col=lane&15 (n), row=(lane>>4)*4+reg (m)
#pragma unroll
  for (int j = 0; j < 4; ++j) {
    const int o    = n0 + wc * 64 + j * 16 + lm;
    const float so = scale[o];
    const float bz = bias[o];
#pragma unroll
    for (int i = 0; i < 4; ++i) {
      const int mbase = m0 + wr * 64 + i * 16 + lk * 4;
#pragma unroll
      for (int r = 0; r < 4; ++r) {
        const int m = mbase + r;
        out[(size_t)m * N_COLS + o] = (float)acc[i][j][r] * (so * srow[m]) + bz;
      }
    }
  }
}

extern "C" void kernel_launch(void* const* d_in, const int* in_sizes, int n_in,
                              void* d_out, int out_size, void* d_ws, size_t ws_size,
                              hipStream_t stream) {
  const float* x     = (const float*)d_in[0];   // [4,2048,4096] fp32
  const int*   q     = (const int*)d_in[1];     // [4096,4096] int32 in [-8,7]
  const float* scale = (const float*)d_in[2];   // [4096]
  const float* bias  = (const float*)d_in[3];   // [4096]
  float* out = (float*)d_out;                   // [8192,4096] fp32

  // workspace: A8 (32 MiB) | B8 (16 MiB) | srow (32 KiB)
  char*  A8   = (char*)d_ws;
  char*  B8   = (char*)d_ws + (size_t)M_ROWS * K_DIM;
  float* srow = (float*)((char*)B8 + (size_t)N_COLS * K_DIM);

  prep_kernel<<<M_ROWS + (N_COLS * K_DIM / 4) / 256, 256, 0, stream>>>(
      (const float4*)x, (int*)A8, srow, (const int4*)q, (int*)B8);

  gemm_i8_kernel<<<2048, 256, 0, stream>>>(A8, B8, scale, srow, bias, out);
}